// Round 11
// baseline (663.187 us; speedup 1.0000x reference)
//
#include <hip/hip_runtime.h>
#include <hip/hip_bf16.h>

// ---------------------------------------------------------------------------
// 2-layer GAT (H=2, C=64) + BN + ELU.  Round 11:
//   - expf -> __expf (v_exp_f32) in gather softmax + gemm ELU (VALU cut).
//   - gather serial accumulate unroll 4 -> 8 (more loads in flight).
//   - everything else identical to Round 10 (MFMA gemm, Round-6 gather).
// Pipeline:
//   memset; wtrans x2; hist; scan_part/psum/final; scatter;
//   gemm_mfma<0> -> h1(bf16)+as/ad; gather<1> -> y(fp32)+BN sums; bn_final;
//   gemm_mfma<1> -> h2(bf16)+as/ad; gather<2> -> out(fp32)
// ---------------------------------------------------------------------------

#define NEG_SLOPE 0.2f
#define BN_EPS 1e-5f
#define SCHUNK 4096

typedef __attribute__((ext_vector_type(8))) short bf16x8;
typedef __attribute__((ext_vector_type(4))) float f32x4;

__device__ __forceinline__ float bf_lo(unsigned int u) { return __uint_as_float(u << 16); }
__device__ __forceinline__ float bf_hi(unsigned int u) { return __uint_as_float(u & 0xffff0000u); }
__device__ __forceinline__ unsigned short f2bf(float v) {
    unsigned int b = __float_as_uint(v);
    b += 0x7fffu + ((b >> 16) & 1u);
    return (unsigned short)(b >> 16);
}

// -------- W pre-transpose: WT[n][k] = bf16(W[k][n]) -------------------------
__global__ __launch_bounds__(256) void wtrans_k(const float* __restrict__ W,
                                                unsigned short* __restrict__ WT) {
    int t = blockIdx.x * 256 + threadIdx.x;   // 64 blocks x 256 = 16384
    int k = t >> 7, n = t & 127;
    WT[n * 128 + k] = f2bf(W[t]);
}

// ------- MFMA GEMM: [nrows,128](fp32->bf16) @ W(bf16,WT) -> bf16 + att dots -
// Block: 256 thr (4 waves), 64 rows. Wave w: rows 16w..16w+15, all 128 cols.
// mfma_f32_16x16x32_bf16 fragments (m89-verified D layout):
//   A: lane l holds X[row0+16w+(l&15)][32ks+8*(l>>4)+j], j=0..7
//   B: lane l holds W[32ks+8*(l>>4)+j][16nt+(l&15)] = Wt[16nt+(l&15)][...]
//   D: lane l holds D[16w+4*(l>>4)+j][16nt+(l&15)], j=0..3
template <int APPLY_ACT>
__global__ __launch_bounds__(256) void gemm_mfma_k(
    const float* __restrict__ X, const unsigned short* __restrict__ WT,
    unsigned short* __restrict__ Out, int nrows, const float* __restrict__ bnparam,
    const float* __restrict__ att_src, const float* __restrict__ att_dst,
    float* __restrict__ as_, float* __restrict__ ad_) {
    __shared__ unsigned short Xt[64][136];    // +8 pad: b128-aligned, ~2-way cfl
    __shared__ unsigned short Wt[128][136];
    int row0 = blockIdx.x * 64;
    int t = threadIdx.x;
    // stage Wt from pre-transposed global (rows of 128 bf16, coalesced uint4)
    for (int i = t; i < 128 * 16; i += 256) {
        int r = i >> 4, c = (i & 15) * 8;
        uint4 v = ((const uint4*)WT)[i];
        *(uint4*)&Wt[r][c] = v;
    }
    // stage Xt: fp32 load, optional BN+ELU, convert bf16
    for (int i = t; i < 64 * 32; i += 256) {
        int r = i >> 5, c4 = i & 31, c = c4 * 4;
        int row = row0 + r;
        float4 v = make_float4(0.f, 0.f, 0.f, 0.f);
        if (row < nrows) v = ((const float4*)X)[(size_t)row * 32 + c4];
        if (APPLY_ACT) {
            float s0 = bnparam[c],     h0 = bnparam[128 + c];
            float s1 = bnparam[c + 1], h1 = bnparam[128 + c + 1];
            float s2 = bnparam[c + 2], h2 = bnparam[128 + c + 2];
            float s3 = bnparam[c + 3], h3 = bnparam[128 + c + 3];
            v.x = s0 * v.x + h0; v.x = v.x > 0.f ? v.x : (__expf(v.x) - 1.f);
            v.y = s1 * v.y + h1; v.y = v.y > 0.f ? v.y : (__expf(v.y) - 1.f);
            v.z = s2 * v.z + h2; v.z = v.z > 0.f ? v.z : (__expf(v.z) - 1.f);
            v.w = s3 * v.w + h3; v.w = v.w > 0.f ? v.w : (__expf(v.w) - 1.f);
        }
        uint2 pk;
        pk.x = (unsigned)f2bf(v.x) | ((unsigned)f2bf(v.y) << 16);
        pk.y = (unsigned)f2bf(v.z) | ((unsigned)f2bf(v.w) << 16);
        *(uint2*)&Xt[r][c] = pk;
    }
    __syncthreads();
    int lane = t & 63, w = t >> 6;
    int lr = lane & 15, lk = lane >> 4;
    f32x4 acc[8] = {};
#pragma unroll
    for (int ks = 0; ks < 4; ++ks) {
        bf16x8 a = *(const bf16x8*)&Xt[16 * w + lr][ks * 32 + 8 * lk];
#pragma unroll
        for (int nt = 0; nt < 8; ++nt) {
            bf16x8 b = *(const bf16x8*)&Wt[16 * nt + lr][ks * 32 + 8 * lk];
            acc[nt] = __builtin_amdgcn_mfma_f32_16x16x32_bf16(a, b, acc[nt], 0, 0, 0);
        }
    }
    // store H (bf16): row = row0+16w+4lk+j, col = 16nt+lr
#pragma unroll
    for (int nt = 0; nt < 8; ++nt) {
#pragma unroll
        for (int j = 0; j < 4; ++j) {
            int row = row0 + 16 * w + 4 * lk + j;
            if (row < nrows)
                Out[(size_t)row * 128 + 16 * nt + lr] = f2bf(acc[nt][j]);
        }
    }
    // attention dots: per row, dot over 128 cols (head0 = 0..63, head1 = 64..127)
    float avs[8], avd[8];
#pragma unroll
    for (int nt = 0; nt < 8; ++nt) {
        avs[nt] = att_src[16 * nt + lr];
        avd[nt] = att_dst[16 * nt + lr];
    }
#pragma unroll
    for (int j = 0; j < 4; ++j) {
        float s0 = 0.f, s1 = 0.f, d0 = 0.f, d1 = 0.f;
#pragma unroll
        for (int nt = 0; nt < 4; ++nt) {
            s0 += acc[nt][j] * avs[nt];
            d0 += acc[nt][j] * avd[nt];
        }
#pragma unroll
        for (int nt = 4; nt < 8; ++nt) {
            s1 += acc[nt][j] * avs[nt];
            d1 += acc[nt][j] * avd[nt];
        }
        for (int off = 8; off; off >>= 1) {
            s0 += __shfl_xor(s0, off);
            s1 += __shfl_xor(s1, off);
            d0 += __shfl_xor(d0, off);
            d1 += __shfl_xor(d1, off);
        }
        int row = row0 + 16 * w + 4 * lk + j;
        if (lr == 0 && row < nrows) {
            as_[row * 2] = s0; as_[row * 2 + 1] = s1;
            ad_[row * 2] = d0; ad_[row * 2 + 1] = d1;
        }
    }
}

// -------- CSR build ---------------------------------------------------------
__global__ __launch_bounds__(256) void hist_k(const int* __restrict__ dst_arr,
                                              int E_, int* __restrict__ cnt) {
    int tid = blockIdx.x * blockDim.x + threadIdx.x;
    int stride = gridDim.x * blockDim.x;
    for (int e = tid; e < E_; e += stride) atomicAdd(&cnt[dst_arr[e]], 1);
}

__global__ __launch_bounds__(256) void scan_part_k(const int* __restrict__ cnt,
                                                   int Nn, int* __restrict__ partial) {
    int b = blockIdx.x;
    int beg = b * SCHUNK, end = min(Nn, beg + SCHUNK);
    int s = 0;
    for (int i = beg + threadIdx.x; i < end; i += 256) s += cnt[i];
    for (int off = 32; off; off >>= 1) s += __shfl_down(s, off);
    __shared__ int wsum[4];
    int lane = threadIdx.x & 63, w = threadIdx.x >> 6;
    if (lane == 0) wsum[w] = s;
    __syncthreads();
    if (threadIdx.x == 0) partial[b] = wsum[0] + wsum[1] + wsum[2] + wsum[3];
}

__global__ void scan_psum_k(int* __restrict__ partial, int NB,
                            int* __restrict__ rowptr, int Nn) {
    if (threadIdx.x == 0) {
        int run = 0;
        for (int i = 0; i < NB; ++i) { int t = partial[i]; partial[i] = run; run += t; }
        rowptr[Nn] = run;
    }
}

__global__ __launch_bounds__(256) void scan_final_k(int* __restrict__ cntcur, int Nn,
                                                    const int* __restrict__ partial,
                                                    int* __restrict__ rowptr) {
    int b = blockIdx.x;
    int t = threadIdx.x;
    int i0 = b * SCHUNK + t * 16;
    int v[16];
    int s = 0;
#pragma unroll
    for (int k = 0; k < 16; ++k) {
        int i = i0 + k;
        int val = (i < Nn) ? cntcur[i] : 0;
        v[k] = s; s += val;
    }
    int lane = t & 63, w = t >> 6;
    int x = s;
    for (int off = 1; off < 64; off <<= 1) {
        int r = __shfl_up(x, off);
        if (lane >= off) x += r;
    }
    __shared__ int wsum[4], woff[4];
    if (lane == 63) wsum[w] = x;
    __syncthreads();
    if (t == 0) { int run = 0; for (int j = 0; j < 4; ++j) { woff[j] = run; run += wsum[j]; } }
    __syncthreads();
    int excl = x - s + woff[w] + partial[b];
#pragma unroll
    for (int k = 0; k < 16; ++k) {
        int i = i0 + k;
        if (i < Nn) { int e = excl + v[k]; rowptr[i] = e; cntcur[i] = e; }
    }
}

__global__ __launch_bounds__(256) void scatter_k(const int* __restrict__ src_arr,
                                                 const int* __restrict__ dst_arr,
                                                 int E_, int* __restrict__ cursor,
                                                 int* __restrict__ csr) {
    int tid = blockIdx.x * blockDim.x + threadIdx.x;
    int stride = gridDim.x * blockDim.x;
    for (int e = tid; e < E_; e += stride) {
        int d = dst_arr[e];
        int pos = atomicAdd(&cursor[d], 1);
        csr[pos] = src_arr[e];
    }
}

// -------- gather: one wave/node, online softmax, __expf, unroll 8 -----------
template <int LAYER>
__global__ __launch_bounds__(256) void gather_k(
    const int* __restrict__ csr, const int* __restrict__ rowptr,
    const float* __restrict__ as_, const float* __restrict__ ad_,
    const unsigned short* __restrict__ hfeat, float* __restrict__ outp,
    const float* __restrict__ bias, float* __restrict__ bnsum, int Nn) {
    __shared__ int4 sPS[4][64];            // per-wave staging {p0,s,p1,s}
    int lane = threadIdx.x & 63;
    int wv = threadIdx.x >> 6;
    int wid = (blockIdx.x * blockDim.x + threadIdx.x) >> 6;
    int nw = (gridDim.x * blockDim.x) >> 6;
    const unsigned int* h4 = (const unsigned int*)hfeat;  // 2 bf16 per uint
    const float2* as2 = (const float2*)as_;
    const float2* ad2 = (const float2*)ad_;
    int head = lane >> 5;
    int4* mPS = sPS[wv];
    const int2* mPS2 = (const int2*)mPS;   // index jj*2 + head
    float bnS0 = 0, bnS1 = 0, bnQ0 = 0, bnQ1 = 0;
    for (int n = wid; n < Nn; n += nw) {
        int beg = rowptr[n], deg = rowptr[n + 1] - beg;
        float2 adn = ad2[n];
        float2 asn = as2[n];
        float es0 = asn.x + adn.x; es0 = es0 > 0.f ? es0 : NEG_SLOPE * es0;
        float es1 = asn.y + adn.y; es1 = es1 > 0.f ? es1 : NEG_SLOPE * es1;
        float m0 = es0, m1 = es1;          // running max per head
        float den0 = 1.f, den1 = 1.f;      // self-loop: p = 1
        unsigned int hu = h4[(size_t)n * 64 + lane];
        float accx = bf_lo(hu), accy = bf_hi(hu);
        for (int j0 = 0; j0 < deg; j0 += 64) {
            int cnt = min(64, deg - j0);
            float t0 = -3.4e38f, t1 = -3.4e38f;
            int s = 0;
            if (lane < cnt) {
                s = csr[beg + j0 + lane];
                float2 a = as2[s];
                t0 = a.x + adn.x; t0 = t0 > 0.f ? t0 : NEG_SLOPE * t0;
                t1 = a.y + adn.y; t1 = t1 > 0.f ? t1 : NEG_SLOPE * t1;
            }
            float cm0 = t0, cm1 = t1;
            for (int off = 32; off; off >>= 1) {
                cm0 = fmaxf(cm0, __shfl_xor(cm0, off));
                cm1 = fmaxf(cm1, __shfl_xor(cm1, off));
            }
            if (cm0 > m0 || cm1 > m1) {    // wave-uniform rescale
                float nm0 = fmaxf(m0, cm0), nm1 = fmaxf(m1, cm1);
                float sc0 = __expf(m0 - nm0), sc1 = __expf(m1 - nm1);
                den0 *= sc0; den1 *= sc1;
                float sch = head ? sc1 : sc0;
                accx *= sch; accy *= sch;
                m0 = nm0; m1 = nm1;
            }
            float p0 = 0.f, p1 = 0.f;
            if (lane < cnt) {
                p0 = __expf(t0 - m0);
                p1 = __expf(t1 - m1);
                mPS[lane] = make_int4(__float_as_int(p0), s, __float_as_int(p1), s);
            }
            float d0 = p0, d1 = p1;
            for (int off = 32; off; off >>= 1) {
                d0 += __shfl_xor(d0, off);
                d1 += __shfl_xor(d1, off);
            }
            den0 += d0; den1 += d1;
            // serial accumulate (wave-private LDS, program order)
#pragma unroll 8
            for (int jj = 0; jj < cnt; ++jj) {
                int2 ps = mPS2[jj * 2 + head];
                float p = __int_as_float(ps.x);
                unsigned off2 = ((unsigned)ps.y << 6) + lane;
                unsigned int hv = h4[off2];
                accx += p * bf_lo(hv);
                accy += p * bf_hi(hv);
            }
        }
        float inv = 1.0f / (head ? den1 : den0);
        if (LAYER == 1) {
            float2 bb = ((const float2*)bias)[lane];
            float2 v; v.x = accx * inv + bb.x; v.y = accy * inv + bb.y;
            ((float2*)outp)[(size_t)n * 64 + lane] = v;
            bnS0 += v.x; bnS1 += v.y; bnQ0 += v.x * v.x; bnQ1 += v.y * v.y;
        } else {
            float vx = accx * inv, vy = accy * inv;
            float vx2 = __shfl(vx, lane + 32);
            float vy2 = __shfl(vy, lane + 32);
            if (lane < 32) {
                float2 bb = ((const float2*)bias)[lane];
                float2 o;
                o.x = 0.5f * (vx + vx2) + bb.x;
                o.y = 0.5f * (vy + vy2) + bb.y;
                ((float2*)outp)[(size_t)n * 32 + lane] = o;
            }
        }
    }
    if (LAYER == 1) {
        __shared__ float lsum[128], lsq[128];
        if (threadIdx.x < 128) { lsum[threadIdx.x] = 0.f; lsq[threadIdx.x] = 0.f; }
        __syncthreads();
        atomicAdd(&lsum[2 * lane], bnS0);
        atomicAdd(&lsum[2 * lane + 1], bnS1);
        atomicAdd(&lsq[2 * lane], bnQ0);
        atomicAdd(&lsq[2 * lane + 1], bnQ1);
        __syncthreads();
        if (threadIdx.x < 128) {
            atomicAdd(&bnsum[threadIdx.x], lsum[threadIdx.x]);
            atomicAdd(&bnsum[128 + threadIdx.x], lsq[threadIdx.x]);
        }
    }
}

// -------- BN param finalize -------------------------------------------------
__global__ void bn_final_k(const float* __restrict__ bnsum,
                           const float* __restrict__ gamma,
                           const float* __restrict__ beta,
                           float* __restrict__ bnparam, float invN) {
    int c = threadIdx.x;
    if (c < 128) {
        float mu = bnsum[c] * invN;
        float var = bnsum[128 + c] * invN - mu * mu;
        float sc = gamma[c] * rsqrtf(var + BN_EPS);
        bnparam[c] = sc;
        bnparam[128 + c] = beta[c] - mu * sc;
    }
}

extern "C" void kernel_launch(void* const* d_in, const int* in_sizes, int n_in,
                              void* d_out, int out_size, void* d_ws, size_t ws_size,
                              hipStream_t stream) {
    const float* x        = (const float*)d_in[0];
    const int*   ei       = (const int*)d_in[1];
    const float* W1       = (const float*)d_in[2];
    const float* att_src1 = (const float*)d_in[3];
    const float* att_dst1 = (const float*)d_in[4];
    const float* b1       = (const float*)d_in[5];
    const float* gamma1   = (const float*)d_in[6];
    const float* beta1    = (const float*)d_in[7];
    const float* W2       = (const float*)d_in[8];
    const float* att_src2 = (const float*)d_in[9];
    const float* att_dst2 = (const float*)d_in[10];
    const float* b2       = (const float*)d_in[11];
    float* out = (float*)d_out;

    const int Nn = in_sizes[0] / 128;
    const int E_ = in_sizes[1] / 2;
    const int* src_arr = ei;
    const int* dst_arr = ei + E_;

    float* ws = (float*)d_ws;
    auto a4 = [](size_t v) { return (v + 3) & ~(size_t)3; };
    size_t off = 0;
    size_t offCnt   = off; off = a4(off + (size_t)Nn);          // cnt/cursor (int)
    size_t offBnsum = off; off = a4(off + 256);                 // zeroed with cnt
    size_t zeroCnt  = off;                                      // [0,zeroCnt) zeroed
    size_t offRow   = off; off = a4(off + (size_t)Nn + 1);      // rowptr (int)
    size_t offPart  = off; off = a4(off + 256);                 // scan partials (int)
    size_t offAs    = off; off = a4(off + (size_t)Nn * 2);
    size_t offAd    = off; off = a4(off + (size_t)Nn * 2);
    size_t offBnp   = off; off = a4(off + 256);
    size_t offWT1   = off; off = a4(off + 8192);                // W1^T bf16 (16K ushort)
    size_t offWT2   = off; off = a4(off + 8192);                // W2^T bf16
    size_t offCsr   = off; off = a4(off + (size_t)E_);          // csr src (int)
    size_t offY     = off; off = a4(off + (size_t)Nn * 128);    // y fp32
    size_t offH1    = off; off = a4(off + (size_t)Nn * 64);     // h1 bf16 (ushort)
    size_t offH2    = off; off = a4(off + (size_t)Nn * 64);     // h2 bf16 (ushort)

    int*   cnt     = (int*)(ws + offCnt);
    float* bnsum   = ws + offBnsum;
    int*   rowptr  = (int*)(ws + offRow);
    int*   partial = (int*)(ws + offPart);
    float* as_     = ws + offAs;
    float* ad_     = ws + offAd;
    float* bnparam = ws + offBnp;
    unsigned short* WT1 = (unsigned short*)(ws + offWT1);
    unsigned short* WT2 = (unsigned short*)(ws + offWT2);
    int*   csr     = (int*)(ws + offCsr);
    float* Y       = ws + offY;
    unsigned short* H1 = (unsigned short*)(ws + offH1);
    unsigned short* H2 = (unsigned short*)(ws + offH2);

    hipMemsetAsync(ws, 0, zeroCnt * sizeof(float), stream);

    // W pre-transposes (independent, cheap)
    wtrans_k<<<64, 256, 0, stream>>>(W1, WT1);
    wtrans_k<<<64, 256, 0, stream>>>(W2, WT2);

    // CSR build
    int NB = (Nn + SCHUNK - 1) / SCHUNK;
    hist_k<<<2048, 256, 0, stream>>>(dst_arr, E_, cnt);
    scan_part_k<<<NB, 256, 0, stream>>>(cnt, Nn, partial);
    scan_psum_k<<<1, 64, 0, stream>>>(partial, NB, rowptr, Nn);
    scan_final_k<<<NB, 256, 0, stream>>>(cnt, Nn, partial, rowptr);
    scatter_k<<<2048, 256, 0, stream>>>(src_arr, dst_arr, E_, cnt, csr);

    int gemmBlocks = (Nn + 63) / 64;
    // layer 1
    gemm_mfma_k<0><<<gemmBlocks, 256, 0, stream>>>(x, WT1, H1, Nn, nullptr,
                                                   att_src1, att_dst1, as_, ad_);
    gather_k<1><<<2048, 256, 0, stream>>>(csr, rowptr, as_, ad_, H1, Y, b1, bnsum, Nn);
    bn_final_k<<<1, 128, 0, stream>>>(bnsum, gamma1, beta1, bnparam, 1.0f / (float)Nn);
    // layer 2
    gemm_mfma_k<1><<<gemmBlocks, 256, 0, stream>>>(Y, WT2, H2, Nn, bnparam,
                                                   att_src2, att_dst2, as_, ad_);
    gather_k<2><<<2048, 256, 0, stream>>>(csr, rowptr, as_, ad_, H2, out, b2, nullptr, Nn);

    (void)n_in; (void)out_size; (void)ws_size;
}

// Round 13
// 612.341 us; speedup vs baseline: 1.0830x; 1.0830x over previous
//
#include <hip/hip_runtime.h>
#include <hip/hip_bf16.h>

// ---------------------------------------------------------------------------
// 2-layer GAT (H=2, C=64) + BN + ELU.  Round 12 (resubmit — broker timeout):
//   - gather: Round-10 body (unroll 4) + __expf only (R11's unroll-8 cost
//     occupancy 70->47; revert).
//   - wtrans1+wtrans2 fused into one launch.
//   - bn_final folded into gemm2 prologue (BN scale/shift computed per-block
//     in LDS from bnsum) — kernel deleted.
// Pipeline:
//   memset; wtrans2; hist; scan_part/psum/final; scatter;
//   gemm_mfma<0> -> h1(bf16)+as/ad; gather<1> -> y(fp32)+BN sums;
//   gemm_mfma<1> (BN fold) -> h2(bf16)+as/ad; gather<2> -> out(fp32)
// ---------------------------------------------------------------------------

#define NEG_SLOPE 0.2f
#define BN_EPS 1e-5f
#define SCHUNK 4096

typedef __attribute__((ext_vector_type(8))) short bf16x8;
typedef __attribute__((ext_vector_type(4))) float f32x4;

__device__ __forceinline__ float bf_lo(unsigned int u) { return __uint_as_float(u << 16); }
__device__ __forceinline__ float bf_hi(unsigned int u) { return __uint_as_float(u & 0xffff0000u); }
__device__ __forceinline__ unsigned short f2bf(float v) {
    unsigned int b = __float_as_uint(v);
    b += 0x7fffu + ((b >> 16) & 1u);
    return (unsigned short)(b >> 16);
}

// -------- W pre-transpose (both weights in one launch) ----------------------
__global__ __launch_bounds__(256) void wtrans2_k(const float* __restrict__ W1,
                                                 const float* __restrict__ W2,
                                                 unsigned short* __restrict__ WT1,
                                                 unsigned short* __restrict__ WT2) {
    int t = blockIdx.x * 256 + threadIdx.x;   // 128 blocks x 256 = 32768
    const float* W = (t < 16384) ? W1 : W2;
    unsigned short* WT = (t < 16384) ? WT1 : WT2;
    int u = t & 16383;
    int k = u >> 7, n = u & 127;
    WT[n * 128 + k] = f2bf(W[u]);
}

// ------- MFMA GEMM: [nrows,128](fp32->bf16) @ W(bf16,WT) -> bf16 + att dots -
// Block: 256 thr (4 waves), 64 rows. Wave w: rows 16w..16w+15, all 128 cols.
// APPLY_ACT: BN params computed in-block from bnsum/gamma/beta, then BN+ELU
// applied during X staging.
template <int APPLY_ACT>
__global__ __launch_bounds__(256) void gemm_mfma_k(
    const float* __restrict__ X, const unsigned short* __restrict__ WT,
    unsigned short* __restrict__ Out, int nrows,
    const float* __restrict__ bnsum, const float* __restrict__ gamma,
    const float* __restrict__ beta, float invN,
    const float* __restrict__ att_src, const float* __restrict__ att_dst,
    float* __restrict__ as_, float* __restrict__ ad_) {
    __shared__ unsigned short Xt[64][136];    // +8 pad
    __shared__ unsigned short Wt[128][136];
    __shared__ float sSc[128], sSh[128];
    int row0 = blockIdx.x * 64;
    int t = threadIdx.x;
    if (APPLY_ACT) {
        if (t < 128) {
            float mu = bnsum[t] * invN;
            float var = bnsum[128 + t] * invN - mu * mu;
            float sc = gamma[t] * rsqrtf(var + BN_EPS);
            sSc[t] = sc;
            sSh[t] = beta[t] - mu * sc;
        }
        __syncthreads();
    }
    // stage Wt from pre-transposed global (rows of 128 bf16, coalesced uint4)
    for (int i = t; i < 128 * 16; i += 256) {
        int r = i >> 4, c = (i & 15) * 8;
        uint4 v = ((const uint4*)WT)[i];
        *(uint4*)&Wt[r][c] = v;
    }
    // stage Xt: fp32 load, optional BN+ELU, convert bf16
    for (int i = t; i < 64 * 32; i += 256) {
        int r = i >> 5, c4 = i & 31, c = c4 * 4;
        int row = row0 + r;
        float4 v = make_float4(0.f, 0.f, 0.f, 0.f);
        if (row < nrows) v = ((const float4*)X)[(size_t)row * 32 + c4];
        if (APPLY_ACT) {
            v.x = sSc[c] * v.x + sSh[c];
            v.y = sSc[c + 1] * v.y + sSh[c + 1];
            v.z = sSc[c + 2] * v.z + sSh[c + 2];
            v.w = sSc[c + 3] * v.w + sSh[c + 3];
            v.x = v.x > 0.f ? v.x : (__expf(v.x) - 1.f);
            v.y = v.y > 0.f ? v.y : (__expf(v.y) - 1.f);
            v.z = v.z > 0.f ? v.z : (__expf(v.z) - 1.f);
            v.w = v.w > 0.f ? v.w : (__expf(v.w) - 1.f);
        }
        uint2 pk;
        pk.x = (unsigned)f2bf(v.x) | ((unsigned)f2bf(v.y) << 16);
        pk.y = (unsigned)f2bf(v.z) | ((unsigned)f2bf(v.w) << 16);
        *(uint2*)&Xt[r][c] = pk;
    }
    __syncthreads();
    int lane = t & 63, w = t >> 6;
    int lr = lane & 15, lk = lane >> 4;
    f32x4 acc[8] = {};
#pragma unroll
    for (int ks = 0; ks < 4; ++ks) {
        bf16x8 a = *(const bf16x8*)&Xt[16 * w + lr][ks * 32 + 8 * lk];
#pragma unroll
        for (int nt = 0; nt < 8; ++nt) {
            bf16x8 b = *(const bf16x8*)&Wt[16 * nt + lr][ks * 32 + 8 * lk];
            acc[nt] = __builtin_amdgcn_mfma_f32_16x16x32_bf16(a, b, acc[nt], 0, 0, 0);
        }
    }
    // store H (bf16): row = row0+16w+4lk+j, col = 16nt+lr
#pragma unroll
    for (int nt = 0; nt < 8; ++nt) {
#pragma unroll
        for (int j = 0; j < 4; ++j) {
            int row = row0 + 16 * w + 4 * lk + j;
            if (row < nrows)
                Out[(size_t)row * 128 + 16 * nt + lr] = f2bf(acc[nt][j]);
        }
    }
    // attention dots
    float avs[8], avd[8];
#pragma unroll
    for (int nt = 0; nt < 8; ++nt) {
        avs[nt] = att_src[16 * nt + lr];
        avd[nt] = att_dst[16 * nt + lr];
    }
#pragma unroll
    for (int j = 0; j < 4; ++j) {
        float s0 = 0.f, s1 = 0.f, d0 = 0.f, d1 = 0.f;
#pragma unroll
        for (int nt = 0; nt < 4; ++nt) {
            s0 += acc[nt][j] * avs[nt];
            d0 += acc[nt][j] * avd[nt];
        }
#pragma unroll
        for (int nt = 4; nt < 8; ++nt) {
            s1 += acc[nt][j] * avs[nt];
            d1 += acc[nt][j] * avd[nt];
        }
        for (int off = 8; off; off >>= 1) {
            s0 += __shfl_xor(s0, off);
            s1 += __shfl_xor(s1, off);
            d0 += __shfl_xor(d0, off);
            d1 += __shfl_xor(d1, off);
        }
        int row = row0 + 16 * w + 4 * lk + j;
        if (lr == 0 && row < nrows) {
            as_[row * 2] = s0; as_[row * 2 + 1] = s1;
            ad_[row * 2] = d0; ad_[row * 2 + 1] = d1;
        }
    }
}

// -------- CSR build ---------------------------------------------------------
__global__ __launch_bounds__(256) void hist_k(const int* __restrict__ dst_arr,
                                              int E_, int* __restrict__ cnt) {
    int tid = blockIdx.x * blockDim.x + threadIdx.x;
    int stride = gridDim.x * blockDim.x;
    for (int e = tid; e < E_; e += stride) atomicAdd(&cnt[dst_arr[e]], 1);
}

__global__ __launch_bounds__(256) void scan_part_k(const int* __restrict__ cnt,
                                                   int Nn, int* __restrict__ partial) {
    int b = blockIdx.x;
    int beg = b * SCHUNK, end = min(Nn, beg + SCHUNK);
    int s = 0;
    for (int i = beg + threadIdx.x; i < end; i += 256) s += cnt[i];
    for (int off = 32; off; off >>= 1) s += __shfl_down(s, off);
    __shared__ int wsum[4];
    int lane = threadIdx.x & 63, w = threadIdx.x >> 6;
    if (lane == 0) wsum[w] = s;
    __syncthreads();
    if (threadIdx.x == 0) partial[b] = wsum[0] + wsum[1] + wsum[2] + wsum[3];
}

__global__ void scan_psum_k(int* __restrict__ partial, int NB,
                            int* __restrict__ rowptr, int Nn) {
    if (threadIdx.x == 0) {
        int run = 0;
        for (int i = 0; i < NB; ++i) { int t = partial[i]; partial[i] = run; run += t; }
        rowptr[Nn] = run;
    }
}

__global__ __launch_bounds__(256) void scan_final_k(int* __restrict__ cntcur, int Nn,
                                                    const int* __restrict__ partial,
                                                    int* __restrict__ rowptr) {
    int b = blockIdx.x;
    int t = threadIdx.x;
    int i0 = b * SCHUNK + t * 16;
    int v[16];
    int s = 0;
#pragma unroll
    for (int k = 0; k < 16; ++k) {
        int i = i0 + k;
        int val = (i < Nn) ? cntcur[i] : 0;
        v[k] = s; s += val;
    }
    int lane = t & 63, w = t >> 6;
    int x = s;
    for (int off = 1; off < 64; off <<= 1) {
        int r = __shfl_up(x, off);
        if (lane >= off) x += r;
    }
    __shared__ int wsum[4], woff[4];
    if (lane == 63) wsum[w] = x;
    __syncthreads();
    if (t == 0) { int run = 0; for (int j = 0; j < 4; ++j) { woff[j] = run; run += wsum[j]; } }
    __syncthreads();
    int excl = x - s + woff[w] + partial[b];
#pragma unroll
    for (int k = 0; k < 16; ++k) {
        int i = i0 + k;
        if (i < Nn) { int e = excl + v[k]; rowptr[i] = e; cntcur[i] = e; }
    }
}

__global__ __launch_bounds__(256) void scatter_k(const int* __restrict__ src_arr,
                                                 const int* __restrict__ dst_arr,
                                                 int E_, int* __restrict__ cursor,
                                                 int* __restrict__ csr) {
    int tid = blockIdx.x * blockDim.x + threadIdx.x;
    int stride = gridDim.x * blockDim.x;
    for (int e = tid; e < E_; e += stride) {
        int d = dst_arr[e];
        int pos = atomicAdd(&cursor[d], 1);
        csr[pos] = src_arr[e];
    }
}

// -------- gather: one wave/node, online softmax, __expf, unroll 4 -----------
template <int LAYER>
__global__ __launch_bounds__(256) void gather_k(
    const int* __restrict__ csr, const int* __restrict__ rowptr,
    const float* __restrict__ as_, const float* __restrict__ ad_,
    const unsigned short* __restrict__ hfeat, float* __restrict__ outp,
    const float* __restrict__ bias, float* __restrict__ bnsum, int Nn) {
    __shared__ int4 sPS[4][64];            // per-wave staging {p0,s,p1,s}
    int lane = threadIdx.x & 63;
    int wv = threadIdx.x >> 6;
    int wid = (blockIdx.x * blockDim.x + threadIdx.x) >> 6;
    int nw = (gridDim.x * blockDim.x) >> 6;
    const unsigned int* h4 = (const unsigned int*)hfeat;  // 2 bf16 per uint
    const float2* as2 = (const float2*)as_;
    const float2* ad2 = (const float2*)ad_;
    int head = lane >> 5;
    int4* mPS = sPS[wv];
    const int2* mPS2 = (const int2*)mPS;   // index jj*2 + head
    float bnS0 = 0, bnS1 = 0, bnQ0 = 0, bnQ1 = 0;
    for (int n = wid; n < Nn; n += nw) {
        int beg = rowptr[n], deg = rowptr[n + 1] - beg;
        float2 adn = ad2[n];
        float2 asn = as2[n];
        float es0 = asn.x + adn.x; es0 = es0 > 0.f ? es0 : NEG_SLOPE * es0;
        float es1 = asn.y + adn.y; es1 = es1 > 0.f ? es1 : NEG_SLOPE * es1;
        float m0 = es0, m1 = es1;          // running max per head
        float den0 = 1.f, den1 = 1.f;      // self-loop: p = 1
        unsigned int hu = h4[(size_t)n * 64 + lane];
        float accx = bf_lo(hu), accy = bf_hi(hu);
        for (int j0 = 0; j0 < deg; j0 += 64) {
            int cnt = min(64, deg - j0);
            float t0 = -3.4e38f, t1 = -3.4e38f;
            int s = 0;
            if (lane < cnt) {
                s = csr[beg + j0 + lane];
                float2 a = as2[s];
                t0 = a.x + adn.x; t0 = t0 > 0.f ? t0 : NEG_SLOPE * t0;
                t1 = a.y + adn.y; t1 = t1 > 0.f ? t1 : NEG_SLOPE * t1;
            }
            float cm0 = t0, cm1 = t1;
            for (int off = 32; off; off >>= 1) {
                cm0 = fmaxf(cm0, __shfl_xor(cm0, off));
                cm1 = fmaxf(cm1, __shfl_xor(cm1, off));
            }
            if (cm0 > m0 || cm1 > m1) {    // wave-uniform rescale
                float nm0 = fmaxf(m0, cm0), nm1 = fmaxf(m1, cm1);
                float sc0 = __expf(m0 - nm0), sc1 = __expf(m1 - nm1);
                den0 *= sc0; den1 *= sc1;
                float sch = head ? sc1 : sc0;
                accx *= sch; accy *= sch;
                m0 = nm0; m1 = nm1;
            }
            float p0 = 0.f, p1 = 0.f;
            if (lane < cnt) {
                p0 = __expf(t0 - m0);
                p1 = __expf(t1 - m1);
                mPS[lane] = make_int4(__float_as_int(p0), s, __float_as_int(p1), s);
            }
            float d0 = p0, d1 = p1;
            for (int off = 32; off; off >>= 1) {
                d0 += __shfl_xor(d0, off);
                d1 += __shfl_xor(d1, off);
            }
            den0 += d0; den1 += d1;
            // serial accumulate (wave-private LDS, program order)
#pragma unroll 4
            for (int jj = 0; jj < cnt; ++jj) {
                int2 ps = mPS2[jj * 2 + head];
                float p = __int_as_float(ps.x);
                unsigned off2 = ((unsigned)ps.y << 6) + lane;
                unsigned int hv = h4[off2];
                accx += p * bf_lo(hv);
                accy += p * bf_hi(hv);
            }
        }
        float inv = 1.0f / (head ? den1 : den0);
        if (LAYER == 1) {
            float2 bb = ((const float2*)bias)[lane];
            float2 v; v.x = accx * inv + bb.x; v.y = accy * inv + bb.y;
            ((float2*)outp)[(size_t)n * 64 + lane] = v;
            bnS0 += v.x; bnS1 += v.y; bnQ0 += v.x * v.x; bnQ1 += v.y * v.y;
        } else {
            float vx = accx * inv, vy = accy * inv;
            float vx2 = __shfl(vx, lane + 32);
            float vy2 = __shfl(vy, lane + 32);
            if (lane < 32) {
                float2 bb = ((const float2*)bias)[lane];
                float2 o;
                o.x = 0.5f * (vx + vx2) + bb.x;
                o.y = 0.5f * (vy + vy2) + bb.y;
                ((float2*)outp)[(size_t)n * 32 + lane] = o;
            }
        }
    }
    if (LAYER == 1) {
        __shared__ float lsum[128], lsq[128];
        if (threadIdx.x < 128) { lsum[threadIdx.x] = 0.f; lsq[threadIdx.x] = 0.f; }
        __syncthreads();
        atomicAdd(&lsum[2 * lane], bnS0);
        atomicAdd(&lsum[2 * lane + 1], bnS1);
        atomicAdd(&lsq[2 * lane], bnQ0);
        atomicAdd(&lsq[2 * lane + 1], bnQ1);
        __syncthreads();
        if (threadIdx.x < 128) {
            atomicAdd(&bnsum[threadIdx.x], lsum[threadIdx.x]);
            atomicAdd(&bnsum[128 + threadIdx.x], lsq[threadIdx.x]);
        }
    }
}

extern "C" void kernel_launch(void* const* d_in, const int* in_sizes, int n_in,
                              void* d_out, int out_size, void* d_ws, size_t ws_size,
                              hipStream_t stream) {
    const float* x        = (const float*)d_in[0];
    const int*   ei       = (const int*)d_in[1];
    const float* W1       = (const float*)d_in[2];
    const float* att_src1 = (const float*)d_in[3];
    const float* att_dst1 = (const float*)d_in[4];
    const float* b1       = (const float*)d_in[5];
    const float* gamma1   = (const float*)d_in[6];
    const float* beta1    = (const float*)d_in[7];
    const float* W2       = (const float*)d_in[8];
    const float* att_src2 = (const float*)d_in[9];
    const float* att_dst2 = (const float*)d_in[10];
    const float* b2       = (const float*)d_in[11];
    float* out = (float*)d_out;

    const int Nn = in_sizes[0] / 128;
    const int E_ = in_sizes[1] / 2;
    const int* src_arr = ei;
    const int* dst_arr = ei + E_;

    float* ws = (float*)d_ws;
    auto a4 = [](size_t v) { return (v + 3) & ~(size_t)3; };
    size_t off = 0;
    size_t offCnt   = off; off = a4(off + (size_t)Nn);          // cnt/cursor (int)
    size_t offBnsum = off; off = a4(off + 256);                 // zeroed with cnt
    size_t zeroCnt  = off;                                      // [0,zeroCnt) zeroed
    size_t offRow   = off; off = a4(off + (size_t)Nn + 1);      // rowptr (int)
    size_t offPart  = off; off = a4(off + 256);                 // scan partials (int)
    size_t offAs    = off; off = a4(off + (size_t)Nn * 2);
    size_t offAd    = off; off = a4(off + (size_t)Nn * 2);
    size_t offWT1   = off; off = a4(off + 8192);                // W1^T bf16
    size_t offWT2   = off; off = a4(off + 8192);                // W2^T bf16
    size_t offCsr   = off; off = a4(off + (size_t)E_);          // csr src (int)
    size_t offY     = off; off = a4(off + (size_t)Nn * 128);    // y fp32
    size_t offH1    = off; off = a4(off + (size_t)Nn * 64);     // h1 bf16 (ushort)
    size_t offH2    = off; off = a4(off + (size_t)Nn * 64);     // h2 bf16 (ushort)

    int*   cnt     = (int*)(ws + offCnt);
    float* bnsum   = ws + offBnsum;
    int*   rowptr  = (int*)(ws + offRow);
    int*   partial = (int*)(ws + offPart);
    float* as_     = ws + offAs;
    float* ad_     = ws + offAd;
    unsigned short* WT1 = (unsigned short*)(ws + offWT1);
    unsigned short* WT2 = (unsigned short*)(ws + offWT2);
    int*   csr     = (int*)(ws + offCsr);
    float* Y       = ws + offY;
    unsigned short* H1 = (unsigned short*)(ws + offH1);
    unsigned short* H2 = (unsigned short*)(ws + offH2);

    hipMemsetAsync(ws, 0, zeroCnt * sizeof(float), stream);

    // W pre-transposes (both in one launch)
    wtrans2_k<<<128, 256, 0, stream>>>(W1, W2, WT1, WT2);

    // CSR build
    int NB = (Nn + SCHUNK - 1) / SCHUNK;
    hist_k<<<2048, 256, 0, stream>>>(dst_arr, E_, cnt);
    scan_part_k<<<NB, 256, 0, stream>>>(cnt, Nn, partial);
    scan_psum_k<<<1, 64, 0, stream>>>(partial, NB, rowptr, Nn);
    scan_final_k<<<NB, 256, 0, stream>>>(cnt, Nn, partial, rowptr);
    scatter_k<<<2048, 256, 0, stream>>>(src_arr, dst_arr, E_, cnt, csr);

    int gemmBlocks = (Nn + 63) / 64;
    // layer 1
    gemm_mfma_k<0><<<gemmBlocks, 256, 0, stream>>>(x, WT1, H1, Nn,
                                                   nullptr, nullptr, nullptr, 0.f,
                                                   att_src1, att_dst1, as_, ad_);
    gather_k<1><<<2048, 256, 0, stream>>>(csr, rowptr, as_, ad_, H1, Y, b1, bnsum, Nn);
    // layer 2 (BN params computed in-kernel from bnsum)
    gemm_mfma_k<1><<<gemmBlocks, 256, 0, stream>>>(Y, WT2, H2, Nn,
                                                   bnsum, gamma1, beta1, 1.0f / (float)Nn,
                                                   att_src2, att_dst2, as_, ad_);
    gather_k<2><<<2048, 256, 0, stream>>>(csr, rowptr, as_, ad_, H2, out, b2, nullptr, Nn);

    (void)n_in; (void)out_size; (void)ws_size;
}